// Round 7
// baseline (158.548 us; speedup 1.0000x reference)
//
#include <hip/hip_runtime.h>
#include <hip/hip_bf16.h>
#include <cstdint>

#define HD 128

typedef __attribute__((ext_vector_type(8))) short short8;
typedef __attribute__((ext_vector_type(4))) float f32x4;
typedef __attribute__((ext_vector_type(4))) unsigned int u32x4;

static __device__ __forceinline__ short bf16_bits(float v) {
    __hip_bfloat16 h = __float2bfloat16(v);
    return __builtin_bit_cast(short, h);
}

// ---------------------------------------------------------------------------
// Mask expand: normalize mask (byte-bool OR int32/fp32 0/1) to float 0/1 in ws.
// Per-block dtype detection: bytes at 4k+1 are nonzero (~50%) only for a
// byte-bool upload; int32/fp32 have 0 there. 256 samples -> P(miss) ~ 2^-256.
// ---------------------------------------------------------------------------
__global__ __launch_bounds__(256) void maskexp_kernel(
    const unsigned char* __restrict__ mask, int n_mask,
    float* __restrict__ mout)
{
    __shared__ int s_byte;
    const int probe = mask[4 * threadIdx.x + 1];
    if (threadIdx.x == 0) s_byte = 0;
    __syncthreads();
    if (probe) atomicOr(&s_byte, 1);
    __syncthreads();
    const bool bytewise = (s_byte != 0);
    const int i0 = (blockIdx.x * 256 + threadIdx.x) * 4;
    if (i0 >= n_mask) return;
    float4 o;
    if (bytewise) {
        const unsigned int b = *reinterpret_cast<const unsigned int*>(mask + i0);
        o.x = (b & 0xffu) ? 1.f : 0.f;
        o.y = (b & 0xff00u) ? 1.f : 0.f;
        o.z = (b & 0xff0000u) ? 1.f : 0.f;
        o.w = (b & 0xff000000u) ? 1.f : 0.f;
    } else {
        const int4 v = *reinterpret_cast<const int4*>((const int*)mask + i0);
        o.x = v.x ? 1.f : 0.f; o.y = v.y ? 1.f : 0.f;
        o.z = v.z ? 1.f : 0.f; o.w = v.w ? 1.f : 0.f;
    }
    *reinterpret_cast<float4*>(mout + i0) = o;
}

// ---------------------------------------------------------------------------
// Pre-cast: W{1,2,3}[d] (fp32, [j_in][m_out]) -> bf16 A-operand image in ws.
// Image s (= d*3+layer): 32 granules p = kb*8+tm of 1024 B (one A-frag);
// lane l owns bytes p*1024 + l*16 .. +15 = 8 bf16 of row m = tm*16 + (l&15),
// logical input j = 32*kb + 16*(jj>>2) + 4*(l>>4) + (jj&3)
// (K-permutation: MFMA D layout == next-layer B layout).
// kb-major => each 16 KB half-image (kb{0,1} | kb{2,3}) is contiguous.
// ---------------------------------------------------------------------------
__global__ __launch_bounds__(256) void precast_kernel(
    const float* __restrict__ W1, const float* __restrict__ W2,
    const float* __restrict__ W3, char* __restrict__ ws)
{
    const int s = blockIdx.x;            // 0..8
    const int d = s / 3, li = s % 3;
    const float* W = (li == 0 ? W1 : li == 1 ? W2 : W3) + d * HD * HD;
    const int t = threadIdx.x;
    const int p = blockIdx.y * 4 + (t >> 6);   // granule 0..31
    const int l = t & 63;
    const int kb = p >> 3, tm = p & 7;
    const int g = l >> 4;
    const int m = tm * 16 + (l & 15);
    const int jbase = 32 * kb + 4 * g;
    unsigned int pk[4];
    #pragma unroll
    for (int w = 0; w < 4; ++w) {
        const int j0 = jbase + (w >> 1) * 16 + (w & 1) * 2;   // jj = 2w
        const float a = W[j0 * HD + m];
        const float b = W[(j0 + 1) * HD + m];
        pk[w] = (unsigned short)bf16_bits(a) |
                ((unsigned)(unsigned short)bf16_bits(b) << 16);
    }
    *reinterpret_cast<u32x4*>(ws + s * 32768 + p * 1024 + l * 16) =
        u32x4{pk[0], pk[1], pk[2], pk[3]};
}

// ---------------------------------------------------------------------------
// Stage one 16 KB half-image (linear, 16 B/lane, 4 iterations).
// ---------------------------------------------------------------------------
static __device__ __forceinline__ void stage_half(const char* __restrict__ src,
                                                  char* dst, int tid)
{
    #pragma unroll
    for (int it = 0; it < 4; ++it)
        __builtin_amdgcn_global_load_lds(
            (const __attribute__((address_space(1))) void*)(src + it * 4096 + tid * 16),
            (__attribute__((address_space(3))) void*)(dst + it * 4096 + tid * 16),
            16, 0, 0);
}

// ---------------------------------------------------------------------------
// Main fused kernel, tc=1: wave owns 16 batch rows, grid 2048 x 4 waves.
// Register budget ~120 total (acc3 32 + acct 32 + bfA/bfB 32 + working)
// => __launch_bounds__(256,4): 4 waves/SIMD, 4 blocks/CU (latency hiding —
// r5/r6 plateaued at 2/SIMD with ~172 regs). Weights streamed through two
// 16 KB K-half LDS buffers: each half's stage overlaps the other half's
// 16 MFMAs, every __syncthreads drains a stage issued one half-layer ago.
// ---------------------------------------------------------------------------
#define MFMA16(A, B, C) __builtin_amdgcn_mfma_f32_16x16x32_bf16(A, B, C, 0, 0, 0)

// one K-half of a mid layer: acct[tm] += A(kb) x BS[kb], kb = KB0, KB0+1
#define HALFL(BUF, BS, KB0)                                                   \
  { _Pragma("unroll")                                                         \
    for (int kk = 0; kk < 2; ++kk) {                                          \
      const int kb = (KB0) + kk;                                              \
      _Pragma("unroll")                                                       \
      for (int tm = 0; tm < 8; ++tm) {                                        \
        const short8 a = *(const short8*)((BUF) + (kk * 8 + tm) * 1024 + lofs);\
        acct[tm] = MFMA16(a, BS[kb], acct[tm]);                               \
      }                                                                       \
    } }

// one K-half of the final layer: acc3 accumulates across d
#define HALFF(BUF, BS, KB0)                                                   \
  { _Pragma("unroll")                                                         \
    for (int kk = 0; kk < 2; ++kk) {                                          \
      const int kb = (KB0) + kk;                                              \
      _Pragma("unroll")                                                       \
      for (int tm = 0; tm < 8; ++tm) {                                        \
        const short8 a = *(const short8*)((BUF) + (kk * 8 + tm) * 1024 + lofs);\
        acc3[tm] = MFMA16(a, BS[kb], acc3[tm]);                               \
      }                                                                       \
    } }

// bias init of acct
#define BIASIN(B)                                                             \
  { _Pragma("unroll")                                                         \
    for (int tm = 0; tm < 8; ++tm)                                            \
      acct[tm] = *(const f32x4*)((B) + tm * 16 + g * 4); }

// acct -> bf16 B-fragments (K-permutation makes D layout == B layout)
#define CONV(DST, DOMASK)                                                     \
  { _Pragma("unroll")                                                         \
    for (int kb = 0; kb < 4; ++kb) {                                          \
      short8 f;                                                               \
      _Pragma("unroll")                                                       \
      for (int hh = 0; hh < 2; ++hh)                                          \
        _Pragma("unroll")                                                     \
        for (int qq = 0; qq < 4; ++qq) {                                      \
          float v = fmaxf(acct[2 * kb + hh][qq], 0.f);                        \
          if (DOMASK) v *= mkf;                                               \
          f[hh * 4 + qq] = bf16_bits(v);                                      \
        }                                                                     \
      DST[kb] = f;                                                            \
    } }

template<bool RAW>
__global__ __launch_bounds__(256, 4) void mlp_kernel(
    const float* __restrict__ x, const float* __restrict__ maskf,
    const unsigned char* __restrict__ maskraw,
    const float* __restrict__ W0, const float* __restrict__ b0,
    const float* __restrict__ b1, const float* __restrict__ b2,
    const float* __restrict__ b3, const char* __restrict__ wsWT,
    float* __restrict__ out)
{
    __shared__ char buf0[16384];
    __shared__ char buf1[16384];
    __shared__ int s_byte;

    const int tid  = threadIdx.x;
    const int wid  = tid >> 6;
    const int lane = tid & 63;
    const int r    = lane & 15;
    const int g    = lane >> 4;
    const int lofs = lane * 16;
    const int row  = blockIdx.x * 64 + wid * 16 + r;

    stage_half(wsWT, buf0, tid);         // H0 of image 0

    bool bytewise = false;
    if constexpr (RAW) {                 // fallback when ws can't hold maskf
        const int probe = maskraw[4 * tid + 1];
        if (tid == 0) s_byte = 0;
        __syncthreads();
        if (probe) atomicOr(&s_byte, 1);
        __syncthreads();
        bytewise = (s_byte != 0);
    }

    f32x4 acc3[8];
    #pragma unroll
    for (int tm = 0; tm < 8; ++tm) acc3[tm] = f32x4{0.f, 0.f, 0.f, 0.f};

    short8 bfA[4], bfB[4];
    f32x4  acct[8];

    for (int d = 0; d < 3; ++d) {
        const int mi = row * 3 + d;
        const float xv = x[mi];
        float mkf;
        if constexpr (RAW)
            mkf = (bytewise ? (maskraw[mi] != 0) : (((const int*)maskraw)[mi] != 0)) ? 1.f : 0.f;
        else
            mkf = maskf[mi];

        // ---- layer 0: h0 = relu(x*W0 + b0) as B-fragments (VALU) ----
        {
            const float* W0d = W0 + d * HD;
            const float* b0d = b0 + d * HD;
            #pragma unroll
            for (int kb = 0; kb < 4; ++kb) {
                short8 f;
                #pragma unroll
                for (int hh = 0; hh < 2; ++hh) {
                    const f32x4 w = *(const f32x4*)(W0d + kb * 32 + hh * 16 + g * 4);
                    const f32x4 b = *(const f32x4*)(b0d + kb * 32 + hh * 16 + g * 4);
                    #pragma unroll
                    for (int qq = 0; qq < 4; ++qq)
                        f[hh * 4 + qq] = bf16_bits(fmaxf(xv * w[qq] + b[qq], 0.f));
                }
                bfA[kb] = f;
            }
        }

        const char* i1 = wsWT + (size_t)(d * 3 + 0) * 32768;
        const char* i2 = wsWT + (size_t)(d * 3 + 1) * 32768;
        const char* i3 = wsWT + (size_t)(d * 3 + 2) * 32768;

        // ---- layer 1 ----
        __syncthreads();                       // buf0 = H0(i1) staged
        stage_half(i1 + 16384, buf1, tid);     // issue H1(i1)
        BIASIN(b1 + d * HD);
        HALFL(buf0, bfA, 0);
        __syncthreads();                       // buf1 staged
        stage_half(i2, buf0, tid);             // issue H0(i2)
        HALFL(buf1, bfA, 2);
        CONV(bfB, false);

        // ---- layer 2 ----
        __syncthreads();
        stage_half(i2 + 16384, buf1, tid);
        BIASIN(b2 + d * HD);
        HALFL(buf0, bfB, 0);
        __syncthreads();
        stage_half(i3, buf0, tid);
        HALFL(buf1, bfB, 2);
        CONV(bfA, true);                       // mask folded into h2

        // ---- layer 3: acc3 += h2 @ W3 ----
        __syncthreads();
        stage_half(i3 + 16384, buf1, tid);
        HALFF(buf0, bfA, 0);
        __syncthreads();
        if (d < 2) stage_half(wsWT + (size_t)(d * 3 + 3) * 32768, buf0, tid);
        HALFF(buf1, bfA, 2);
    }

    // ---- epilogue: + sum_d mask_d * b3_d, store fp32 16 B ----
    float mk[3];
    #pragma unroll
    for (int dd = 0; dd < 3; ++dd) {
        const int mi = row * 3 + dd;
        if constexpr (RAW)
            mk[dd] = (bytewise ? (maskraw[mi] != 0) : (((const int*)maskraw)[mi] != 0)) ? 1.f : 0.f;
        else
            mk[dd] = maskf[mi];
    }
    float* orow = out + (long)row * HD;
    #pragma unroll
    for (int tm = 0; tm < 8; ++tm) {
        const f32x4 ba  = *(const f32x4*)(b3 + 0 * HD + tm * 16 + g * 4);
        const f32x4 bbv = *(const f32x4*)(b3 + 1 * HD + tm * 16 + g * 4);
        const f32x4 bc  = *(const f32x4*)(b3 + 2 * HD + tm * 16 + g * 4);
        f32x4 o = acc3[tm];
        #pragma unroll
        for (int qq = 0; qq < 4; ++qq)
            o[qq] += mk[0] * ba[qq] + mk[1] * bbv[qq] + mk[2] * bc[qq];
        *reinterpret_cast<f32x4*>(orow + tm * 16 + g * 4) = o;
    }
}

extern "C" void kernel_launch(void* const* d_in, const int* in_sizes, int n_in,
                              void* d_out, int out_size, void* d_ws, size_t ws_size,
                              hipStream_t stream) {
    const float* x  = (const float*)d_in[0];
    const unsigned char* mask = (const unsigned char*)d_in[1];
    const float* W0 = (const float*)d_in[2];
    const float* b0 = (const float*)d_in[3];
    const float* W1 = (const float*)d_in[4];
    const float* b1 = (const float*)d_in[5];
    const float* W2 = (const float*)d_in[6];
    const float* b2 = (const float*)d_in[7];
    const float* W3 = (const float*)d_in[8];
    const float* b3 = (const float*)d_in[9];
    float* out = (float*)d_out;
    char* ws = (char*)d_ws;
    const int n_mask = in_sizes[1];                    // N*D elements
    float* maskf = (float*)(ws + 9 * 32768);
    const size_t need = 9 * 32768 + (size_t)n_mask * 4;

    hipLaunchKernelGGL(precast_kernel, dim3(9, 8), dim3(256), 0, stream,
                       W1, W2, W3, ws);
    if (ws_size >= need) {
        hipLaunchKernelGGL(maskexp_kernel, dim3((n_mask + 1023) / 1024), dim3(256),
                           0, stream, mask, n_mask, maskf);
        hipLaunchKernelGGL((mlp_kernel<false>), dim3(2048), dim3(256), 0, stream,
                           x, maskf, mask, W0, b0, b1, b2, b3, ws, out);
    } else {
        hipLaunchKernelGGL((mlp_kernel<true>), dim3(2048), dim3(256), 0, stream,
                           x, nullptr, mask, W0, b0, b1, b2, b3, ws, out);
    }
}